// Round 1
// baseline (502.364 us; speedup 1.0000x reference)
//
#include <hip/hip_runtime.h>
#include <math.h>

#define N_NODES 50000
#define E_EDGES 1600000
#define IN_C 128
#define HC 128          // HEADS*OUT_C
#define NEG_SLOPE 0.2f

// ---------------------------------------------------------------------------
// Kernel 1: h = x @ W  (50000x128 @ 128x128), fused a_src/a_dst epilogue.
// Tile: 32 rows/block-iter, thread computes 4 rows x 4 cols.
// LDS: W 64KB + x-tile 16KB -> 2 blocks/CU.
// ---------------------------------------------------------------------------
__global__ __launch_bounds__(256, 2)
void gemm_attn_kernel(const float* __restrict__ x, const float* __restrict__ W,
                      const float* __restrict__ att_src, const float* __restrict__ att_dst,
                      float* __restrict__ h, float* __restrict__ a_src,
                      float* __restrict__ a_dst)
{
    __shared__ float Ws[128 * 128];   // 64 KB
    __shared__ float xs[32 * 128];    // 16 KB

    const int tid = threadIdx.x;
    const int c4  = tid & 31;   // column-quad index: cols c4*4 .. c4*4+3
    const int rg  = tid >> 5;   // row group 0..7, rows rg*4 .. rg*4+3 in tile

    // stage W once per block (coalesced float4)
    for (int i = tid; i < 128 * 128 / 4; i += 256)
        ((float4*)Ws)[i] = ((const float4*)W)[i];

    // attention vectors for this thread's 4 columns (att flat layout == col)
    const float4 asv = ((const float4*)att_src)[c4];
    const float4 adv = ((const float4*)att_dst)[c4];
    const int head = c4 >> 2;   // col0/16

    const float4* Ws4 = (const float4*)Ws;
    const float4* xs4 = (const float4*)xs;

    for (int tile = blockIdx.x; tile * 32 < N_NODES; tile += gridDim.x) {
        const int row_base = tile * 32;
        // stage 32 rows of x (4096 floats = 1024 float4)
        for (int i = tid; i < 32 * 128 / 4; i += 256) {
            const int r  = i >> 5;
            const int gr = row_base + r;
            float4 v = make_float4(0.f, 0.f, 0.f, 0.f);
            if (gr < N_NODES) v = ((const float4*)x)[gr * 32 + (i & 31)];
            ((float4*)xs)[i] = v;
        }
        __syncthreads();   // covers W staging on first iteration too

        float4 acc[4];
        #pragma unroll
        for (int r = 0; r < 4; ++r) acc[r] = make_float4(0.f, 0.f, 0.f, 0.f);

        #pragma unroll 4
        for (int k4 = 0; k4 < 32; ++k4) {
            const float4 w0 = Ws4[(4 * k4 + 0) * 32 + c4];
            const float4 w1 = Ws4[(4 * k4 + 1) * 32 + c4];
            const float4 w2 = Ws4[(4 * k4 + 2) * 32 + c4];
            const float4 w3 = Ws4[(4 * k4 + 3) * 32 + c4];
            #pragma unroll
            for (int r = 0; r < 4; ++r) {
                const float4 xv = xs4[(rg * 4 + r) * 32 + k4];
                acc[r].x = fmaf(xv.x, w0.x, acc[r].x);
                acc[r].y = fmaf(xv.x, w0.y, acc[r].y);
                acc[r].z = fmaf(xv.x, w0.z, acc[r].z);
                acc[r].w = fmaf(xv.x, w0.w, acc[r].w);
                acc[r].x = fmaf(xv.y, w1.x, acc[r].x);
                acc[r].y = fmaf(xv.y, w1.y, acc[r].y);
                acc[r].z = fmaf(xv.y, w1.z, acc[r].z);
                acc[r].w = fmaf(xv.y, w1.w, acc[r].w);
                acc[r].x = fmaf(xv.z, w2.x, acc[r].x);
                acc[r].y = fmaf(xv.z, w2.y, acc[r].y);
                acc[r].z = fmaf(xv.z, w2.z, acc[r].z);
                acc[r].w = fmaf(xv.z, w2.w, acc[r].w);
                acc[r].x = fmaf(xv.w, w3.x, acc[r].x);
                acc[r].y = fmaf(xv.w, w3.y, acc[r].y);
                acc[r].z = fmaf(xv.w, w3.z, acc[r].z);
                acc[r].w = fmaf(xv.w, w3.w, acc[r].w);
            }
        }

        #pragma unroll
        for (int r = 0; r < 4; ++r) {
            const int row = row_base + rg * 4 + r;
            if (row < N_NODES) {
                ((float4*)h)[row * 32 + c4] = acc[r];
                // per-head attention dot: reduce across the 4 lanes of a head
                float ps = acc[r].x * asv.x + acc[r].y * asv.y +
                           acc[r].z * asv.z + acc[r].w * asv.w;
                float pd = acc[r].x * adv.x + acc[r].y * adv.y +
                           acc[r].z * adv.z + acc[r].w * adv.w;
                ps += __shfl_xor(ps, 1, 64); ps += __shfl_xor(ps, 2, 64);
                pd += __shfl_xor(pd, 1, 64); pd += __shfl_xor(pd, 2, 64);
                if ((c4 & 3) == 0) {
                    a_src[row * 8 + head] = ps;
                    a_dst[row * 8 + head] = pd;
                }
            }
        }
        __syncthreads();
    }
}

// ---------------------------------------------------------------------------
// CSR build: histogram -> 2-phase exclusive scan -> scatter
// ---------------------------------------------------------------------------
__global__ __launch_bounds__(256)
void hist_kernel(const int* __restrict__ ei, int* __restrict__ deg)
{
    for (int i = blockIdx.x * blockDim.x + threadIdx.x; i < E_EDGES;
         i += gridDim.x * blockDim.x) {
        atomicAdd(&deg[ei[E_EDGES + i]], 1);   // dst row
    }
}

__global__ __launch_bounds__(256)
void scan1_kernel(const int* __restrict__ deg, int* __restrict__ offs,
                  int* __restrict__ bsums)
{
    __shared__ int s[256];
    const int i = blockIdx.x * 256 + threadIdx.x;
    const int v = (i < N_NODES) ? deg[i] : 0;
    s[threadIdx.x] = v;
    __syncthreads();
    #pragma unroll
    for (int d = 1; d < 256; d <<= 1) {
        int t = (threadIdx.x >= d) ? s[threadIdx.x - d] : 0;
        __syncthreads();
        s[threadIdx.x] += t;
        __syncthreads();
    }
    if (i < N_NODES) offs[i] = s[threadIdx.x] - v;  // exclusive
    if (threadIdx.x == 255) bsums[blockIdx.x] = s[255];
}

__global__ __launch_bounds__(256)
void scan2_kernel(int* __restrict__ offs, const int* __restrict__ bsums,
                  int* __restrict__ cursor)
{
    int partial = 0;
    for (int j = threadIdx.x; j < (int)blockIdx.x; j += 256) partial += bsums[j];
    #pragma unroll
    for (int d = 32; d >= 1; d >>= 1) partial += __shfl_down(partial, d, 64);
    __shared__ int wsum[4];
    if ((threadIdx.x & 63) == 0) wsum[threadIdx.x >> 6] = partial;
    __syncthreads();
    const int base = wsum[0] + wsum[1] + wsum[2] + wsum[3];
    const int i = blockIdx.x * 256 + threadIdx.x;
    if (i < N_NODES) {
        const int o = offs[i] + base;
        offs[i] = o;
        cursor[i] = o;
    }
}

__global__ __launch_bounds__(256)
void scatter_kernel(const int* __restrict__ ei, int* __restrict__ cursor,
                    int* __restrict__ csr_src)
{
    for (int i = blockIdx.x * blockDim.x + threadIdx.x; i < E_EDGES;
         i += gridDim.x * blockDim.x) {
        const int s = ei[i];
        const int d = ei[E_EDGES + i];
        const int pos = atomicAdd(&cursor[d], 1);
        csr_src[pos] = s;
    }
}

// ---------------------------------------------------------------------------
// Kernel 3: fused softmax + aggregation. One wave per destination node.
// Lane owns channels 2*lane, 2*lane+1 (head = lane/8).
// out = relu( (sum ex*h[src]) / (sum ex + 1e-16) + bias )
// ---------------------------------------------------------------------------
__global__ __launch_bounds__(256)
void aggregate_kernel(const int* __restrict__ offs, const int* __restrict__ cursor,
                      const int* __restrict__ csr_src,
                      const float* __restrict__ h, const float* __restrict__ a_src,
                      const float* __restrict__ a_dst, const float* __restrict__ bias,
                      float* __restrict__ out)
{
    const int node = blockIdx.x * 4 + (threadIdx.x >> 6);
    if (node >= N_NODES) return;
    const int lane = threadIdx.x & 63;
    const int head = lane >> 3;

    const int start = offs[node];
    const int end   = cursor[node];          // offs[node] + deg[node]
    const float ad  = a_dst[node * 8 + head];

    float accx = 0.f, accy = 0.f, den = 0.f;
    for (int j = start; j < end; ++j) {
        const int src = csr_src[j];
        const float logit = a_src[src * 8 + head] + ad;
        const float e  = (logit > 0.f) ? logit : logit * NEG_SLOPE;
        const float ex = __expf(e);
        const float2 hv = ((const float2*)h)[src * 64 + lane];
        accx = fmaf(ex, hv.x, accx);
        accy = fmaf(ex, hv.y, accy);
        den += ex;
    }
    const float inv = 1.0f / (den + 1e-16f);
    const float2 b = ((const float2*)bias)[lane];
    float o0 = fmaf(accx, inv, 0.f) + b.x;
    float o1 = fmaf(accy, inv, 0.f) + b.y;
    float2 res;
    res.x = fmaxf(o0, 0.f);
    res.y = fmaxf(o1, 0.f);
    ((float2*)out)[node * 64 + lane] = res;
}

// ---------------------------------------------------------------------------
extern "C" void kernel_launch(void* const* d_in, const int* in_sizes, int n_in,
                              void* d_out, int out_size, void* d_ws, size_t ws_size,
                              hipStream_t stream)
{
    const float* x       = (const float*)d_in[0];
    // d_in[1] = x_0 (unused by reference)
    const float* W       = (const float*)d_in[2];
    const float* att_src = (const float*)d_in[3];
    const float* att_dst = (const float*)d_in[4];
    const float* bias    = (const float*)d_in[5];
    const int*   ei      = (const int*)d_in[6];   // [2][E]: row0=src, row1=dst

    float* out = (float*)d_out;

    // workspace layout
    float* h      = (float*)d_ws;                 // 6,400,000 f
    float* a_src  = h + (size_t)N_NODES * HC;     //   400,000 f
    float* a_dst  = a_src + (size_t)N_NODES * 8;  //   400,000 f
    int*   deg    = (int*)(a_dst + (size_t)N_NODES * 8);  // 50,000 i
    int*   offs   = deg + N_NODES;                //    50,000 i
    int*   cursor = offs + N_NODES;               //    50,000 i
    int*   bsums  = cursor + N_NODES;             //       256 i
    int*   csr    = bsums + 256;                  // 1,600,000 i

    // 1) projection + attention logits
    hipLaunchKernelGGL(gemm_attn_kernel, dim3(512), dim3(256), 0, stream,
                       x, W, att_src, att_dst, h, a_src, a_dst);

    // 2) CSR build
    hipMemsetAsync(deg, 0, N_NODES * sizeof(int), stream);
    hipLaunchKernelGGL(hist_kernel, dim3(2048), dim3(256), 0, stream, ei, deg);

    const int nblk = (N_NODES + 255) / 256;       // 196
    hipLaunchKernelGGL(scan1_kernel, dim3(nblk), dim3(256), 0, stream,
                       deg, offs, bsums);
    hipLaunchKernelGGL(scan2_kernel, dim3(nblk), dim3(256), 0, stream,
                       offs, bsums, cursor);
    hipLaunchKernelGGL(scatter_kernel, dim3(2048), dim3(256), 0, stream,
                       ei, cursor, csr);

    // 3) fused softmax + weighted aggregation (+bias +relu)
    hipLaunchKernelGGL(aggregate_kernel, dim3((N_NODES + 3) / 4), dim3(256), 0,
                       stream, offs, cursor, csr, h, a_src, a_dst, bias, out);
}

// Round 3
// 452.711 us; speedup vs baseline: 1.1097x; 1.1097x over previous
//
#include <hip/hip_runtime.h>
#include <math.h>

#define N_NODES 50000
#define E_EDGES 1600000
#define IN_C 128
#define HC 128          // HEADS*OUT_C
#define NEG_SLOPE 0.2f

// ---------------------------------------------------------------------------
// Kernel 1: h = x @ W  (50000x128 @ 128x128), fused a_src/a_dst epilogue.
// Tile: 32 rows/block-iter, thread computes 4 rows x 4 cols.
// LDS: W 64KB + x-tile 16KB -> 2 blocks/CU.
// ---------------------------------------------------------------------------
__global__ __launch_bounds__(256, 2)
void gemm_attn_kernel(const float* __restrict__ x, const float* __restrict__ W,
                      const float* __restrict__ att_src, const float* __restrict__ att_dst,
                      float* __restrict__ h, float* __restrict__ a_src,
                      float* __restrict__ a_dst)
{
    __shared__ float Ws[128 * 128];   // 64 KB
    __shared__ float xs[32 * 128];    // 16 KB

    const int tid = threadIdx.x;
    const int c4  = tid & 31;   // column-quad index: cols c4*4 .. c4*4+3
    const int rg  = tid >> 5;   // row group 0..7, rows rg*4 .. rg*4+3 in tile

    // stage W once per block (coalesced float4)
    for (int i = tid; i < 128 * 128 / 4; i += 256)
        ((float4*)Ws)[i] = ((const float4*)W)[i];

    // attention vectors for this thread's 4 columns (att flat layout == col)
    const float4 asv = ((const float4*)att_src)[c4];
    const float4 adv = ((const float4*)att_dst)[c4];
    const int head = c4 >> 2;   // col0/16

    const float4* Ws4 = (const float4*)Ws;
    const float4* xs4 = (const float4*)xs;

    for (int tile = blockIdx.x; tile * 32 < N_NODES; tile += gridDim.x) {
        const int row_base = tile * 32;
        // stage 32 rows of x (4096 floats = 1024 float4)
        for (int i = tid; i < 32 * 128 / 4; i += 256) {
            const int r  = i >> 5;
            const int gr = row_base + r;
            float4 v = make_float4(0.f, 0.f, 0.f, 0.f);
            if (gr < N_NODES) v = ((const float4*)x)[gr * 32 + (i & 31)];
            ((float4*)xs)[i] = v;
        }
        __syncthreads();   // covers W staging on first iteration too

        float4 acc[4];
        #pragma unroll
        for (int r = 0; r < 4; ++r) acc[r] = make_float4(0.f, 0.f, 0.f, 0.f);

        #pragma unroll 4
        for (int k4 = 0; k4 < 32; ++k4) {
            const float4 w0 = Ws4[(4 * k4 + 0) * 32 + c4];
            const float4 w1 = Ws4[(4 * k4 + 1) * 32 + c4];
            const float4 w2 = Ws4[(4 * k4 + 2) * 32 + c4];
            const float4 w3 = Ws4[(4 * k4 + 3) * 32 + c4];
            #pragma unroll
            for (int r = 0; r < 4; ++r) {
                const float4 xv = xs4[(rg * 4 + r) * 32 + k4];
                acc[r].x = fmaf(xv.x, w0.x, acc[r].x);
                acc[r].y = fmaf(xv.x, w0.y, acc[r].y);
                acc[r].z = fmaf(xv.x, w0.z, acc[r].z);
                acc[r].w = fmaf(xv.x, w0.w, acc[r].w);
                acc[r].x = fmaf(xv.y, w1.x, acc[r].x);
                acc[r].y = fmaf(xv.y, w1.y, acc[r].y);
                acc[r].z = fmaf(xv.y, w1.z, acc[r].z);
                acc[r].w = fmaf(xv.y, w1.w, acc[r].w);
                acc[r].x = fmaf(xv.z, w2.x, acc[r].x);
                acc[r].y = fmaf(xv.z, w2.y, acc[r].y);
                acc[r].z = fmaf(xv.z, w2.z, acc[r].z);
                acc[r].w = fmaf(xv.z, w2.w, acc[r].w);
                acc[r].x = fmaf(xv.w, w3.x, acc[r].x);
                acc[r].y = fmaf(xv.w, w3.y, acc[r].y);
                acc[r].z = fmaf(xv.w, w3.z, acc[r].z);
                acc[r].w = fmaf(xv.w, w3.w, acc[r].w);
            }
        }

        #pragma unroll
        for (int r = 0; r < 4; ++r) {
            const int row = row_base + rg * 4 + r;
            if (row < N_NODES) {
                ((float4*)h)[row * 32 + c4] = acc[r];
                // per-head attention dot: reduce across the 4 lanes of a head
                float ps = acc[r].x * asv.x + acc[r].y * asv.y +
                           acc[r].z * asv.z + acc[r].w * asv.w;
                float pd = acc[r].x * adv.x + acc[r].y * adv.y +
                           acc[r].z * adv.z + acc[r].w * adv.w;
                ps += __shfl_xor(ps, 1, 64); ps += __shfl_xor(ps, 2, 64);
                pd += __shfl_xor(pd, 1, 64); pd += __shfl_xor(pd, 2, 64);
                if ((c4 & 3) == 0) {
                    a_src[row * 8 + head] = ps;
                    a_dst[row * 8 + head] = pd;
                }
            }
        }
        __syncthreads();
    }
}

// ---------------------------------------------------------------------------
// CSR build: histogram -> 2-phase exclusive scan -> scatter
// ---------------------------------------------------------------------------
__global__ __launch_bounds__(256)
void hist_kernel(const int* __restrict__ ei, int* __restrict__ deg)
{
    for (int i = blockIdx.x * blockDim.x + threadIdx.x; i < E_EDGES;
         i += gridDim.x * blockDim.x) {
        atomicAdd(&deg[ei[E_EDGES + i]], 1);   // dst row
    }
}

__global__ __launch_bounds__(256)
void scan1_kernel(const int* __restrict__ deg, int* __restrict__ offs,
                  int* __restrict__ bsums)
{
    __shared__ int s[256];
    const int i = blockIdx.x * 256 + threadIdx.x;
    const int v = (i < N_NODES) ? deg[i] : 0;
    s[threadIdx.x] = v;
    __syncthreads();
    #pragma unroll
    for (int d = 1; d < 256; d <<= 1) {
        int t = (threadIdx.x >= d) ? s[threadIdx.x - d] : 0;
        __syncthreads();
        s[threadIdx.x] += t;
        __syncthreads();
    }
    if (i < N_NODES) offs[i] = s[threadIdx.x] - v;  // exclusive
    if (threadIdx.x == 255) bsums[blockIdx.x] = s[255];
}

__global__ __launch_bounds__(256)
void scan2_kernel(int* __restrict__ offs, const int* __restrict__ bsums,
                  int* __restrict__ cursor)
{
    int partial = 0;
    for (int j = threadIdx.x; j < (int)blockIdx.x; j += 256) partial += bsums[j];
    #pragma unroll
    for (int d = 32; d >= 1; d >>= 1) partial += __shfl_down(partial, d, 64);
    __shared__ int wsum[4];
    if ((threadIdx.x & 63) == 0) wsum[threadIdx.x >> 6] = partial;
    __syncthreads();
    const int base = wsum[0] + wsum[1] + wsum[2] + wsum[3];
    const int i = blockIdx.x * 256 + threadIdx.x;
    if (i < N_NODES) {
        const int o = offs[i] + base;
        offs[i] = o;
        cursor[i] = o;
    }
}

__global__ __launch_bounds__(256)
void scatter_kernel(const int* __restrict__ ei, int* __restrict__ cursor,
                    int* __restrict__ csr_src)
{
    for (int i = blockIdx.x * blockDim.x + threadIdx.x; i < E_EDGES;
         i += gridDim.x * blockDim.x) {
        const int s = ei[i];
        const int d = ei[E_EDGES + i];
        const int pos = atomicAdd(&cursor[d], 1);
        csr_src[pos] = s;
    }
}

// ---------------------------------------------------------------------------
// Kernel 3: fused softmax + aggregation. One wave per destination node.
// Lane owns channels 2*lane, 2*lane+1 (head = lane/8).
// v2: 8-way edge unroll — batch index loads, then batch gathers, so each
// wave keeps 8 independent 512B h-gathers in flight (MLP) instead of 1.
// All unrolled arrays statically indexed (full unroll) so they stay in VGPRs.
// ---------------------------------------------------------------------------
__global__ __launch_bounds__(256)
void aggregate_kernel(const int* __restrict__ offs, const int* __restrict__ oend,
                      const int* __restrict__ csr_src,
                      const float* __restrict__ h, const float* __restrict__ a_src,
                      const float* __restrict__ a_dst, const float* __restrict__ bias,
                      float* __restrict__ out)
{
    const int node = blockIdx.x * 4 + (threadIdx.x >> 6);
    if (node >= N_NODES) return;
    const int lane = threadIdx.x & 63;
    const int head = lane >> 3;

    const int start = offs[node];
    const int end   = oend[node];            // offs[node] + deg[node]
    const float ad  = a_dst[node * 8 + head];
    const float2* __restrict__ h2 = (const float2*)h;

    float accx = 0.f, accy = 0.f, den = 0.f;
    int j = start;
    for (; j + 8 <= end; j += 8) {
        int s[8];
        #pragma unroll
        for (int u = 0; u < 8; ++u) s[u] = csr_src[j + u];
        float lg[8];
        #pragma unroll
        for (int u = 0; u < 8; ++u) lg[u] = a_src[s[u] * 8 + head] + ad;
        float2 hv[8];
        #pragma unroll
        for (int u = 0; u < 8; ++u) hv[u] = h2[s[u] * 64 + lane];
        #pragma unroll
        for (int u = 0; u < 8; ++u) {
            const float e  = (lg[u] > 0.f) ? lg[u] : lg[u] * NEG_SLOPE;
            const float ex = __expf(e);
            accx = fmaf(ex, hv[u].x, accx);
            accy = fmaf(ex, hv[u].y, accy);
            den += ex;
        }
    }
    for (; j < end; ++j) {
        const int src = csr_src[j];
        const float logit = a_src[src * 8 + head] + ad;
        const float e  = (logit > 0.f) ? logit : logit * NEG_SLOPE;
        const float ex = __expf(e);
        const float2 hv = h2[src * 64 + lane];
        accx = fmaf(ex, hv.x, accx);
        accy = fmaf(ex, hv.y, accy);
        den += ex;
    }
    const float inv = 1.0f / (den + 1e-16f);
    const float2 b = ((const float2*)bias)[lane];
    float2 res;
    res.x = fmaxf(fmaf(accx, inv, b.x), 0.f);
    res.y = fmaxf(fmaf(accy, inv, b.y), 0.f);
    ((float2*)out)[node * 64 + lane] = res;
}

// ---------------------------------------------------------------------------
extern "C" void kernel_launch(void* const* d_in, const int* in_sizes, int n_in,
                              void* d_out, int out_size, void* d_ws, size_t ws_size,
                              hipStream_t stream)
{
    const float* x       = (const float*)d_in[0];
    // d_in[1] = x_0 (unused by reference)
    const float* W       = (const float*)d_in[2];
    const float* att_src = (const float*)d_in[3];
    const float* att_dst = (const float*)d_in[4];
    const float* bias    = (const float*)d_in[5];
    const int*   ei      = (const int*)d_in[6];   // [2][E]: row0=src, row1=dst

    float* out = (float*)d_out;

    // workspace layout
    float* h      = (float*)d_ws;                 // 6,400,000 f
    float* a_src  = h + (size_t)N_NODES * HC;     //   400,000 f
    float* a_dst  = a_src + (size_t)N_NODES * 8;  //   400,000 f
    int*   deg    = (int*)(a_dst + (size_t)N_NODES * 8);  // 50,000 i
    int*   offs   = deg + N_NODES;                //    50,000 i
    int*   cursor = offs + N_NODES;               //    50,000 i
    int*   bsums  = cursor + N_NODES;             //       256 i
    int*   csr    = bsums + 256;                  // 1,600,000 i

    // 1) projection + attention logits
    hipLaunchKernelGGL(gemm_attn_kernel, dim3(512), dim3(256), 0, stream,
                       x, W, att_src, att_dst, h, a_src, a_dst);

    // 2) CSR build
    hipMemsetAsync(deg, 0, N_NODES * sizeof(int), stream);
    hipLaunchKernelGGL(hist_kernel, dim3(2048), dim3(256), 0, stream, ei, deg);

    const int nblk = (N_NODES + 255) / 256;       // 196
    hipLaunchKernelGGL(scan1_kernel, dim3(nblk), dim3(256), 0, stream,
                       deg, offs, bsums);
    hipLaunchKernelGGL(scan2_kernel, dim3(nblk), dim3(256), 0, stream,
                       offs, bsums, cursor);
    hipLaunchKernelGGL(scatter_kernel, dim3(2048), dim3(256), 0, stream,
                       ei, cursor, csr);

    // 3) fused softmax + weighted aggregation (+bias +relu)
    hipLaunchKernelGGL(aggregate_kernel, dim3((N_NODES + 3) / 4), dim3(256), 0,
                       stream, offs, cursor, csr, h, a_src, a_dst, bias, out);
}

// Round 6
// 393.156 us; speedup vs baseline: 1.2778x; 1.1515x over previous
//
#include <hip/hip_runtime.h>
#include <hip/hip_fp16.h>
#include <math.h>

#define N_NODES 50000
#define E_EDGES 1600000
#define IN_C 128
#define HC 128          // HEADS*OUT_C
#define NEG_SLOPE 0.2f
#define PAD 16          // one int32 counter per 64B cache line

// ---------------------------------------------------------------------------
// Kernel 1: h = x @ W  (50000x128 @ 128x128), fused a_src/a_dst epilogue.
// h is stored as fp16 (halves the aggregate gather traffic; |h|~N(0,1) so
// fp16 range is safe and mantissa err 2^-12 is invisible vs f32 reference).
// a_src/a_dst are computed from the f32 accumulators (full precision).
// ---------------------------------------------------------------------------
__global__ __launch_bounds__(256, 2)
void gemm_attn_kernel(const float* __restrict__ x, const float* __restrict__ W,
                      const float* __restrict__ att_src, const float* __restrict__ att_dst,
                      __half* __restrict__ h, float* __restrict__ a_src,
                      float* __restrict__ a_dst)
{
    __shared__ float Ws[128 * 128];   // 64 KB
    __shared__ float xs[32 * 128];    // 16 KB

    const int tid = threadIdx.x;
    const int c4  = tid & 31;   // column-quad index: cols c4*4 .. c4*4+3
    const int rg  = tid >> 5;   // row group 0..7

    for (int i = tid; i < 128 * 128 / 4; i += 256)
        ((float4*)Ws)[i] = ((const float4*)W)[i];

    const float4 asv = ((const float4*)att_src)[c4];
    const float4 adv = ((const float4*)att_dst)[c4];
    const int head = c4 >> 2;

    const float4* Ws4 = (const float4*)Ws;
    const float4* xs4 = (const float4*)xs;

    for (int tile = blockIdx.x; tile * 32 < N_NODES; tile += gridDim.x) {
        const int row_base = tile * 32;
        for (int i = tid; i < 32 * 128 / 4; i += 256) {
            const int r  = i >> 5;
            const int gr = row_base + r;
            float4 v = make_float4(0.f, 0.f, 0.f, 0.f);
            if (gr < N_NODES) v = ((const float4*)x)[gr * 32 + (i & 31)];
            ((float4*)xs)[i] = v;
        }
        __syncthreads();

        float4 acc[4];
        #pragma unroll
        for (int r = 0; r < 4; ++r) acc[r] = make_float4(0.f, 0.f, 0.f, 0.f);

        #pragma unroll 4
        for (int k4 = 0; k4 < 32; ++k4) {
            const float4 w0 = Ws4[(4 * k4 + 0) * 32 + c4];
            const float4 w1 = Ws4[(4 * k4 + 1) * 32 + c4];
            const float4 w2 = Ws4[(4 * k4 + 2) * 32 + c4];
            const float4 w3 = Ws4[(4 * k4 + 3) * 32 + c4];
            #pragma unroll
            for (int r = 0; r < 4; ++r) {
                const float4 xv = xs4[(rg * 4 + r) * 32 + k4];
                acc[r].x = fmaf(xv.x, w0.x, acc[r].x);
                acc[r].y = fmaf(xv.x, w0.y, acc[r].y);
                acc[r].z = fmaf(xv.x, w0.z, acc[r].z);
                acc[r].w = fmaf(xv.x, w0.w, acc[r].w);
                acc[r].x = fmaf(xv.y, w1.x, acc[r].x);
                acc[r].y = fmaf(xv.y, w1.y, acc[r].y);
                acc[r].z = fmaf(xv.y, w1.z, acc[r].z);
                acc[r].w = fmaf(xv.y, w1.w, acc[r].w);
                acc[r].x = fmaf(xv.z, w2.x, acc[r].x);
                acc[r].y = fmaf(xv.z, w2.y, acc[r].y);
                acc[r].z = fmaf(xv.z, w2.z, acc[r].z);
                acc[r].w = fmaf(xv.z, w2.w, acc[r].w);
                acc[r].x = fmaf(xv.w, w3.x, acc[r].x);
                acc[r].y = fmaf(xv.w, w3.y, acc[r].y);
                acc[r].z = fmaf(xv.w, w3.z, acc[r].z);
                acc[r].w = fmaf(xv.w, w3.w, acc[r].w);
            }
        }

        #pragma unroll
        for (int r = 0; r < 4; ++r) {
            const int row = row_base + rg * 4 + r;
            if (row < N_NODES) {
                // pack 4 channels -> 2x half2 -> one 8B store
                const __half2 p0 = __floats2half2_rn(acc[r].x, acc[r].y);
                const __half2 p1 = __floats2half2_rn(acc[r].z, acc[r].w);
                uint2 pk;
                pk.x = *(const unsigned int*)&p0;
                pk.y = *(const unsigned int*)&p1;
                ((uint2*)h)[row * 32 + c4] = pk;

                float ps = acc[r].x * asv.x + acc[r].y * asv.y +
                           acc[r].z * asv.z + acc[r].w * asv.w;
                float pd = acc[r].x * adv.x + acc[r].y * adv.y +
                           acc[r].z * adv.z + acc[r].w * adv.w;
                ps += __shfl_xor(ps, 1, 64); ps += __shfl_xor(ps, 2, 64);
                pd += __shfl_xor(pd, 1, 64); pd += __shfl_xor(pd, 2, 64);
                if ((c4 & 3) == 0) {
                    a_src[row * 8 + head] = ps;
                    a_dst[row * 8 + head] = pd;
                }
            }
        }
        __syncthreads();
    }
}

// ---------------------------------------------------------------------------
// CSR build. degcur is the PADDED deg/cursor array: counter i lives at
// degcur[i*PAD] so every counter owns a full 64B line (kills per-line
// serialization of device-scope atomic RMWs).
// Lifecycle: hist atomics deg -> scan1 reads deg -> scan2 overwrites slot
// with cursor start -> scatter atomics cursor -> aggregate reads it as end.
// ---------------------------------------------------------------------------
__global__ __launch_bounds__(256)
void hist_kernel(const int* __restrict__ ei, int* __restrict__ degcur)
{
    for (int i = blockIdx.x * blockDim.x + threadIdx.x; i < E_EDGES;
         i += gridDim.x * blockDim.x) {
        atomicAdd(&degcur[ei[E_EDGES + i] * PAD], 1);   // dst row
    }
}

__global__ __launch_bounds__(256)
void scan1_kernel(const int* __restrict__ degcur, int* __restrict__ offs,
                  int* __restrict__ bsums)
{
    __shared__ int s[256];
    const int i = blockIdx.x * 256 + threadIdx.x;
    const int v = (i < N_NODES) ? degcur[i * PAD] : 0;
    s[threadIdx.x] = v;
    __syncthreads();
    #pragma unroll
    for (int d = 1; d < 256; d <<= 1) {
        int t = (threadIdx.x >= d) ? s[threadIdx.x - d] : 0;
        __syncthreads();
        s[threadIdx.x] += t;
        __syncthreads();
    }
    if (i < N_NODES) offs[i] = s[threadIdx.x] - v;  // exclusive
    if (threadIdx.x == 255) bsums[blockIdx.x] = s[255];
}

__global__ __launch_bounds__(256)
void scan2_kernel(int* __restrict__ offs, const int* __restrict__ bsums,
                  int* __restrict__ degcur)
{
    int partial = 0;
    for (int j = threadIdx.x; j < (int)blockIdx.x; j += 256) partial += bsums[j];
    #pragma unroll
    for (int d = 32; d >= 1; d >>= 1) partial += __shfl_down(partial, d, 64);
    __shared__ int wsum[4];
    if ((threadIdx.x & 63) == 0) wsum[threadIdx.x >> 6] = partial;
    __syncthreads();
    const int base = wsum[0] + wsum[1] + wsum[2] + wsum[3];
    const int i = blockIdx.x * 256 + threadIdx.x;
    if (i < N_NODES) {
        const int o = offs[i] + base;
        offs[i] = o;
        degcur[i * PAD] = o;   // becomes the scatter cursor
    }
}

// 8 edges/thread: 8 independent atomics in flight before the dependent
// stores (MLP), instead of one serialized round-trip per grid-stride iter.
__global__ __launch_bounds__(256)
void scatter_kernel(const int* __restrict__ ei, int* __restrict__ degcur,
                    int* __restrict__ csr_src)
{
    const int base = (blockIdx.x * 256 + threadIdx.x) * 8;
    if (base >= E_EDGES) return;   // E_EDGES % 8 == 0 -> full chunk valid
    int s[8], d[8], pos[8];
    #pragma unroll
    for (int u = 0; u < 8; ++u) s[u] = ei[base + u];
    #pragma unroll
    for (int u = 0; u < 8; ++u) d[u] = ei[E_EDGES + base + u];
    #pragma unroll
    for (int u = 0; u < 8; ++u) pos[u] = atomicAdd(&degcur[d[u] * PAD], 1);
    #pragma unroll
    for (int u = 0; u < 8; ++u) csr_src[pos[u]] = s[u];
}

// ---------------------------------------------------------------------------
// Kernel 3: fused softmax + aggregation. One wave per destination node.
// Lane owns channels 2*lane, 2*lane+1 (head = lane/8); h gather is fp16
// (4B/lane = 256B/wave/edge). 8-way edge unroll keeps 8 gathers in flight.
// ---------------------------------------------------------------------------
__global__ __launch_bounds__(256)
void aggregate_kernel(const int* __restrict__ offs, const int* __restrict__ degcur,
                      const int* __restrict__ csr_src,
                      const __half* __restrict__ h, const float* __restrict__ a_src,
                      const float* __restrict__ a_dst, const float* __restrict__ bias,
                      float* __restrict__ out)
{
    const int node = blockIdx.x * 4 + (threadIdx.x >> 6);
    if (node >= N_NODES) return;
    const int lane = threadIdx.x & 63;
    const int head = lane >> 3;

    const int start = offs[node];
    const int end   = degcur[node * PAD];    // offs + deg
    const float ad  = a_dst[node * 8 + head];
    const __half2* __restrict__ h2 = (const __half2*)h;

    float accx = 0.f, accy = 0.f, den = 0.f;
    int j = start;
    for (; j + 8 <= end; j += 8) {
        int s[8];
        #pragma unroll
        for (int u = 0; u < 8; ++u) s[u] = csr_src[j + u];
        float lg[8];
        #pragma unroll
        for (int u = 0; u < 8; ++u) lg[u] = a_src[s[u] * 8 + head] + ad;
        __half2 hv[8];
        #pragma unroll
        for (int u = 0; u < 8; ++u) hv[u] = h2[s[u] * 64 + lane];
        #pragma unroll
        for (int u = 0; u < 8; ++u) {
            const float e  = (lg[u] > 0.f) ? lg[u] : lg[u] * NEG_SLOPE;
            const float ex = __expf(e);
            const float2 f = __half22float2(hv[u]);
            accx = fmaf(ex, f.x, accx);
            accy = fmaf(ex, f.y, accy);
            den += ex;
        }
    }
    for (; j < end; ++j) {
        const int src = csr_src[j];
        const float logit = a_src[src * 8 + head] + ad;
        const float e  = (logit > 0.f) ? logit : logit * NEG_SLOPE;
        const float ex = __expf(e);
        const float2 f = __half22float2(h2[src * 64 + lane]);
        accx = fmaf(ex, f.x, accx);
        accy = fmaf(ex, f.y, accy);
        den += ex;
    }
    const float inv = 1.0f / (den + 1e-16f);
    const float2 b = ((const float2*)bias)[lane];
    float2 res;
    res.x = fmaxf(fmaf(accx, inv, b.x), 0.f);
    res.y = fmaxf(fmaf(accy, inv, b.y), 0.f);
    ((float2*)out)[node * 64 + lane] = res;
}

// ---------------------------------------------------------------------------
extern "C" void kernel_launch(void* const* d_in, const int* in_sizes, int n_in,
                              void* d_out, int out_size, void* d_ws, size_t ws_size,
                              hipStream_t stream)
{
    const float* x       = (const float*)d_in[0];
    // d_in[1] = x_0 (unused by reference)
    const float* W       = (const float*)d_in[2];
    const float* att_src = (const float*)d_in[3];
    const float* att_dst = (const float*)d_in[4];
    const float* bias    = (const float*)d_in[5];
    const int*   ei      = (const int*)d_in[6];   // [2][E]: row0=src, row1=dst

    float* out = (float*)d_out;

    // workspace layout (~26 MB)
    __half* h     = (__half*)d_ws;                    // N*128 halves (12.8MB)
    float* a_src  = (float*)(h + (size_t)N_NODES * HC);  // 400,000 f
    float* a_dst  = a_src + (size_t)N_NODES * 8;      //   400,000 f
    int*   degcur = (int*)(a_dst + (size_t)N_NODES * 8); // 800,000 i (padded)
    int*   offs   = degcur + (size_t)N_NODES * PAD;   //    50,000 i
    int*   bsums  = offs + N_NODES;                   //       256 i
    int*   csr    = bsums + 256;                      // 1,600,000 i

    // 1) projection + attention logits
    hipLaunchKernelGGL(gemm_attn_kernel, dim3(512), dim3(256), 0, stream,
                       x, W, att_src, att_dst, h, a_src, a_dst);

    // 2) CSR build
    hipMemsetAsync(degcur, 0, (size_t)N_NODES * PAD * sizeof(int), stream);
    hipLaunchKernelGGL(hist_kernel, dim3(2048), dim3(256), 0, stream, ei, degcur);

    const int nblk = (N_NODES + 255) / 256;           // 196
    hipLaunchKernelGGL(scan1_kernel, dim3(nblk), dim3(256), 0, stream,
                       degcur, offs, bsums);
    hipLaunchKernelGGL(scan2_kernel, dim3(nblk), dim3(256), 0, stream,
                       offs, bsums, degcur);
    hipLaunchKernelGGL(scatter_kernel, dim3((E_EDGES / 8 + 255) / 256), dim3(256),
                       0, stream, ei, degcur, csr);

    // 3) fused softmax + weighted aggregation (+bias +relu)
    hipLaunchKernelGGL(aggregate_kernel, dim3((N_NODES + 3) / 4), dim3(256), 0,
                       stream, offs, degcur, csr, h, a_src, a_dst, bias, out);
}

// Round 10
// 318.933 us; speedup vs baseline: 1.5751x; 1.2327x over previous
//
#include <hip/hip_runtime.h>
#include <hip/hip_fp16.h>
#include <math.h>

#define N_NODES 50000
#define E_EDGES 1600000
#define IN_C 128
#define HC 128          // HEADS*OUT_C
#define NEG_SLOPE 0.2f
#define PAD 16          // one int32 counter per 64B cache line
#define NB 391          // buckets: 128 nodes each, ceil(50000/128)

// ---------------------------------------------------------------------------
// Kernel 1: h = x @ W  (50000x128 @ 128x128), fused a_src/a_dst epilogue.
// h stored fp16 (halves aggregate gather traffic; |h|~N(0,1): range safe).
// ---------------------------------------------------------------------------
__global__ __launch_bounds__(256, 2)
void gemm_attn_kernel(const float* __restrict__ x, const float* __restrict__ W,
                      const float* __restrict__ att_src, const float* __restrict__ att_dst,
                      __half* __restrict__ h, float* __restrict__ a_src,
                      float* __restrict__ a_dst)
{
    __shared__ float Ws[128 * 128];   // 64 KB
    __shared__ float xs[32 * 128];    // 16 KB

    const int tid = threadIdx.x;
    const int c4  = tid & 31;
    const int rg  = tid >> 5;

    for (int i = tid; i < 128 * 128 / 4; i += 256)
        ((float4*)Ws)[i] = ((const float4*)W)[i];

    const float4 asv = ((const float4*)att_src)[c4];
    const float4 adv = ((const float4*)att_dst)[c4];
    const int head = c4 >> 2;

    const float4* Ws4 = (const float4*)Ws;
    const float4* xs4 = (const float4*)xs;

    for (int tile = blockIdx.x; tile * 32 < N_NODES; tile += gridDim.x) {
        const int row_base = tile * 32;
        for (int i = tid; i < 32 * 128 / 4; i += 256) {
            const int r  = i >> 5;
            const int gr = row_base + r;
            float4 v = make_float4(0.f, 0.f, 0.f, 0.f);
            if (gr < N_NODES) v = ((const float4*)x)[gr * 32 + (i & 31)];
            ((float4*)xs)[i] = v;
        }
        __syncthreads();

        float4 acc[4];
        #pragma unroll
        for (int r = 0; r < 4; ++r) acc[r] = make_float4(0.f, 0.f, 0.f, 0.f);

        #pragma unroll 4
        for (int k4 = 0; k4 < 32; ++k4) {
            const float4 w0 = Ws4[(4 * k4 + 0) * 32 + c4];
            const float4 w1 = Ws4[(4 * k4 + 1) * 32 + c4];
            const float4 w2 = Ws4[(4 * k4 + 2) * 32 + c4];
            const float4 w3 = Ws4[(4 * k4 + 3) * 32 + c4];
            #pragma unroll
            for (int r = 0; r < 4; ++r) {
                const float4 xv = xs4[(rg * 4 + r) * 32 + k4];
                acc[r].x = fmaf(xv.x, w0.x, acc[r].x);
                acc[r].y = fmaf(xv.x, w0.y, acc[r].y);
                acc[r].z = fmaf(xv.x, w0.z, acc[r].z);
                acc[r].w = fmaf(xv.x, w0.w, acc[r].w);
                acc[r].x = fmaf(xv.y, w1.x, acc[r].x);
                acc[r].y = fmaf(xv.y, w1.y, acc[r].y);
                acc[r].z = fmaf(xv.y, w1.z, acc[r].z);
                acc[r].w = fmaf(xv.y, w1.w, acc[r].w);
                acc[r].x = fmaf(xv.z, w2.x, acc[r].x);
                acc[r].y = fmaf(xv.z, w2.y, acc[r].y);
                acc[r].z = fmaf(xv.z, w2.z, acc[r].z);
                acc[r].w = fmaf(xv.z, w2.w, acc[r].w);
                acc[r].x = fmaf(xv.w, w3.x, acc[r].x);
                acc[r].y = fmaf(xv.w, w3.y, acc[r].y);
                acc[r].z = fmaf(xv.w, w3.z, acc[r].z);
                acc[r].w = fmaf(xv.w, w3.w, acc[r].w);
            }
        }

        #pragma unroll
        for (int r = 0; r < 4; ++r) {
            const int row = row_base + rg * 4 + r;
            if (row < N_NODES) {
                const __half2 p0 = __floats2half2_rn(acc[r].x, acc[r].y);
                const __half2 p1 = __floats2half2_rn(acc[r].z, acc[r].w);
                uint2 pk;
                pk.x = *(const unsigned int*)&p0;
                pk.y = *(const unsigned int*)&p1;
                ((uint2*)h)[row * 32 + c4] = pk;

                float ps = acc[r].x * asv.x + acc[r].y * asv.y +
                           acc[r].z * asv.z + acc[r].w * asv.w;
                float pd = acc[r].x * adv.x + acc[r].y * adv.y +
                           acc[r].z * adv.z + acc[r].w * adv.w;
                ps += __shfl_xor(ps, 1, 64); ps += __shfl_xor(ps, 2, 64);
                pd += __shfl_xor(pd, 1, 64); pd += __shfl_xor(pd, 2, 64);
                if ((c4 & 3) == 0) {
                    a_src[row * 8 + head] = ps;
                    a_dst[row * 8 + head] = pd;
                }
            }
        }
        __syncthreads();
    }
}

// ---------------------------------------------------------------------------
// CSR build v3: two-phase bucket sort. Bucket = dst>>7 (128 nodes/bucket).
// cntA: per-block LDS bucket histogram -> ~100K flush atomics (vs 1.6M).
// scanB: 1-block exclusive scan of 391 bucket counts -> base, init cursors.
// splitA: per-edge atomic on 391 HOT padded cursors; packed 4B (dst|src)
//         store lands densely per bucket -> L2 assembles full lines ->
//         write amplification ~1x (was 16x).
// phaseB: block per bucket: LDS counting sort over 128 nodes; csr stores
//         random only within a 16KB L2-resident region; emits dense
//         offs/oend. Replaces hist/scan1/scan2.
// ---------------------------------------------------------------------------
__global__ __launch_bounds__(256)
void cntA_kernel(const int* __restrict__ ei, int* __restrict__ gcnt)
{
    __shared__ int lcnt[NB];
    for (int i = threadIdx.x; i < NB; i += 256) lcnt[i] = 0;
    __syncthreads();
    for (int i = blockIdx.x * 256 + threadIdx.x; i < E_EDGES;
         i += gridDim.x * 256) {
        atomicAdd(&lcnt[ei[E_EDGES + i] >> 7], 1);
    }
    __syncthreads();
    for (int i = threadIdx.x; i < NB; i += 256)
        if (lcnt[i] > 0) atomicAdd(&gcnt[i * PAD], lcnt[i]);
}

__global__ __launch_bounds__(512)
void scanB_kernel(const int* __restrict__ gcnt, int* __restrict__ base,
                  int* __restrict__ cursor)
{
    __shared__ int s[512];
    const int t = threadIdx.x;
    const int v = (t < NB) ? gcnt[t * PAD] : 0;
    s[t] = v;
    __syncthreads();
    #pragma unroll
    for (int d = 1; d < 512; d <<= 1) {
        int x = (t >= d) ? s[t - d] : 0;
        __syncthreads();
        s[t] += x;
        __syncthreads();
    }
    if (t < NB) {
        const int e = s[t] - v;          // exclusive
        base[t] = e;
        cursor[t * PAD] = e;
    }
    if (t == NB - 1) base[NB] = s[t];    // == E_EDGES
}

__global__ __launch_bounds__(256)
void splitA_kernel(const int* __restrict__ ei, int* __restrict__ cursor,
                   unsigned int* __restrict__ bpairs)
{
    const int base_e = (blockIdx.x * 256 + threadIdx.x) * 8;
    if (base_e >= E_EDGES) return;      // E%8==0 -> full chunk valid
    int s[8], d[8], pos[8];
    #pragma unroll
    for (int u = 0; u < 8; ++u) s[u] = ei[base_e + u];
    #pragma unroll
    for (int u = 0; u < 8; ++u) d[u] = ei[E_EDGES + base_e + u];
    #pragma unroll
    for (int u = 0; u < 8; ++u) pos[u] = atomicAdd(&cursor[(d[u] >> 7) * PAD], 1);
    #pragma unroll
    for (int u = 0; u < 8; ++u)
        bpairs[pos[u]] = ((unsigned)d[u] << 16) | (unsigned)s[u];
}

__global__ __launch_bounds__(256)
void phaseB_kernel(const int* __restrict__ base,
                   const unsigned int* __restrict__ bpairs,
                   int* __restrict__ csr, int* __restrict__ offs,
                   int* __restrict__ oend)
{
    const int b  = blockIdx.x;
    const int lo = base[b];
    const int hi = base[b + 1];
    const int node0 = b << 7;
    const int t = threadIdx.x;

    __shared__ int cnt[128], loff[128], cur[128];
    if (t < 128) cnt[t] = 0;
    __syncthreads();

    for (int i = lo + t; i < hi; i += 256) {
        const int ld = (int)(bpairs[i] >> 16) - node0;
        atomicAdd(&cnt[ld], 1);
    }
    __syncthreads();

    if (t < 128) loff[t] = cnt[t];
    __syncthreads();
    #pragma unroll
    for (int d = 1; d < 128; d <<= 1) {
        int x = (t >= d && t < 128) ? loff[t - d] : 0;
        __syncthreads();
        if (t < 128) loff[t] += x;
        __syncthreads();
    }
    if (t < 128) {
        const int e = loff[t] - cnt[t];  // exclusive
        cur[t] = e;
        const int node = node0 + t;
        if (node < N_NODES) {
            offs[node] = lo + e;
            oend[node] = lo + e + cnt[t];
        }
    }
    __syncthreads();

    for (int i = lo + t; i < hi; i += 256) {
        const unsigned p = bpairs[i];
        const int ld = (int)(p >> 16) - node0;
        const int pos = lo + atomicAdd(&cur[ld], 1);
        csr[pos] = (int)(p & 0xFFFFu);
    }
}

// ---------------------------------------------------------------------------
// Kernel 3: fused softmax + aggregation. One wave per destination node.
// fp16 h gather (4B/lane); 8-way edge unroll keeps 8 gathers in flight.
// ---------------------------------------------------------------------------
__global__ __launch_bounds__(256)
void aggregate_kernel(const int* __restrict__ offs, const int* __restrict__ oend,
                      const int* __restrict__ csr_src,
                      const __half* __restrict__ h, const float* __restrict__ a_src,
                      const float* __restrict__ a_dst, const float* __restrict__ bias,
                      float* __restrict__ out)
{
    const int node = blockIdx.x * 4 + (threadIdx.x >> 6);
    if (node >= N_NODES) return;
    const int lane = threadIdx.x & 63;
    const int head = lane >> 3;

    const int start = offs[node];
    const int end   = oend[node];
    const float ad  = a_dst[node * 8 + head];
    const __half2* __restrict__ h2 = (const __half2*)h;

    float accx = 0.f, accy = 0.f, den = 0.f;
    int j = start;
    for (; j + 8 <= end; j += 8) {
        int s[8];
        #pragma unroll
        for (int u = 0; u < 8; ++u) s[u] = csr_src[j + u];
        float lg[8];
        #pragma unroll
        for (int u = 0; u < 8; ++u) lg[u] = a_src[s[u] * 8 + head] + ad;
        __half2 hv[8];
        #pragma unroll
        for (int u = 0; u < 8; ++u) hv[u] = h2[s[u] * 64 + lane];
        #pragma unroll
        for (int u = 0; u < 8; ++u) {
            const float e  = (lg[u] > 0.f) ? lg[u] : lg[u] * NEG_SLOPE;
            const float ex = __expf(e);
            const float2 f = __half22float2(hv[u]);
            accx = fmaf(ex, f.x, accx);
            accy = fmaf(ex, f.y, accy);
            den += ex;
        }
    }
    for (; j < end; ++j) {
        const int src = csr_src[j];
        const float logit = a_src[src * 8 + head] + ad;
        const float e  = (logit > 0.f) ? logit : logit * NEG_SLOPE;
        const float ex = __expf(e);
        const float2 f = __half22float2(h2[src * 64 + lane]);
        accx = fmaf(ex, f.x, accx);
        accy = fmaf(ex, f.y, accy);
        den += ex;
    }
    const float inv = 1.0f / (den + 1e-16f);
    const float2 b = ((const float2*)bias)[lane];
    float2 res;
    res.x = fmaxf(fmaf(accx, inv, b.x), 0.f);
    res.y = fmaxf(fmaf(accy, inv, b.y), 0.f);
    ((float2*)out)[node * 64 + lane] = res;
}

// ---------------------------------------------------------------------------
extern "C" void kernel_launch(void* const* d_in, const int* in_sizes, int n_in,
                              void* d_out, int out_size, void* d_ws, size_t ws_size,
                              hipStream_t stream)
{
    const float* x       = (const float*)d_in[0];
    // d_in[1] = x_0 (unused by reference)
    const float* W       = (const float*)d_in[2];
    const float* att_src = (const float*)d_in[3];
    const float* att_dst = (const float*)d_in[4];
    const float* bias    = (const float*)d_in[5];
    const int*   ei      = (const int*)d_in[6];   // [2][E]: row0=src, row1=dst

    float* out = (float*)d_out;

    // workspace layout (~29.5 MB)
    __half* h     = (__half*)d_ws;                        // 12.8 MB
    float* a_src  = (float*)(h + (size_t)N_NODES * HC);   // 1.6 MB
    float* a_dst  = a_src + (size_t)N_NODES * 8;          // 1.6 MB
    int*   offs   = (int*)(a_dst + (size_t)N_NODES * 8);  // 200 KB
    int*   oend   = offs + N_NODES;                       // 200 KB
    int*   gcnt   = oend + N_NODES;                       // NB*PAD ints
    int*   base   = gcnt + NB * PAD;                      // NB+1 ints
    int*   cursor = base + (NB + 1);                      // NB*PAD ints
    unsigned int* bpairs = (unsigned int*)(cursor + NB * PAD); // 6.4 MB
    int*   csr    = (int*)(bpairs + E_EDGES);             // 6.4 MB

    // 1) projection + attention logits
    hipLaunchKernelGGL(gemm_attn_kernel, dim3(512), dim3(256), 0, stream,
                       x, W, att_src, att_dst, h, a_src, a_dst);

    // 2) CSR build (two-phase bucket sort)
    hipMemsetAsync(gcnt, 0, (size_t)NB * PAD * sizeof(int), stream);
    hipLaunchKernelGGL(cntA_kernel, dim3(256), dim3(256), 0, stream, ei, gcnt);
    hipLaunchKernelGGL(scanB_kernel, dim3(1), dim3(512), 0, stream,
                       gcnt, base, cursor);
    hipLaunchKernelGGL(splitA_kernel, dim3((E_EDGES / 8 + 255) / 256), dim3(256),
                       0, stream, ei, cursor, bpairs);
    hipLaunchKernelGGL(phaseB_kernel, dim3(NB), dim3(256), 0, stream,
                       base, bpairs, csr, offs, oend);

    // 3) fused softmax + weighted aggregation (+bias +relu)
    hipLaunchKernelGGL(aggregate_kernel, dim3((N_NODES + 3) / 4), dim3(256), 0,
                       stream, offs, oend, csr, h, a_src, a_dst, bias, out);
}

// Round 15
// 277.860 us; speedup vs baseline: 1.8080x; 1.1478x over previous
//
#include <hip/hip_runtime.h>
#include <hip/hip_fp16.h>
#include <math.h>

#define N_NODES 50000
#define E_EDGES 1600000
#define IN_C 128
#define HC 128          // HEADS*OUT_C
#define NEG_SLOPE 0.2f
#define PAD 16          // one int32 counter per 64B cache line
#define NB 391          // buckets: 128 nodes each, ceil(50000/128)
#define CHUNK 8192      // edges per splitA block
#define KPT 32          // edges per thread (256 threads)

// ---------------------------------------------------------------------------
// Kernel 1: h = x @ W  (50000x128 @ 128x128), fused a_src/a_dst epilogue.
// h stored fp16 (halves aggregate gather traffic; |h|~N(0,1): range safe).
// ---------------------------------------------------------------------------
__global__ __launch_bounds__(256, 2)
void gemm_attn_kernel(const float* __restrict__ x, const float* __restrict__ W,
                      const float* __restrict__ att_src, const float* __restrict__ att_dst,
                      __half* __restrict__ h, float* __restrict__ a_src,
                      float* __restrict__ a_dst)
{
    __shared__ float Ws[128 * 128];   // 64 KB
    __shared__ float xs[32 * 128];    // 16 KB

    const int tid = threadIdx.x;
    const int c4  = tid & 31;
    const int rg  = tid >> 5;

    for (int i = tid; i < 128 * 128 / 4; i += 256)
        ((float4*)Ws)[i] = ((const float4*)W)[i];

    const float4 asv = ((const float4*)att_src)[c4];
    const float4 adv = ((const float4*)att_dst)[c4];
    const int head = c4 >> 2;

    const float4* Ws4 = (const float4*)Ws;
    const float4* xs4 = (const float4*)xs;

    for (int tile = blockIdx.x; tile * 32 < N_NODES; tile += gridDim.x) {
        const int row_base = tile * 32;
        for (int i = tid; i < 32 * 128 / 4; i += 256) {
            const int r  = i >> 5;
            const int gr = row_base + r;
            float4 v = make_float4(0.f, 0.f, 0.f, 0.f);
            if (gr < N_NODES) v = ((const float4*)x)[gr * 32 + (i & 31)];
            ((float4*)xs)[i] = v;
        }
        __syncthreads();

        float4 acc[4];
        #pragma unroll
        for (int r = 0; r < 4; ++r) acc[r] = make_float4(0.f, 0.f, 0.f, 0.f);

        #pragma unroll 4
        for (int k4 = 0; k4 < 32; ++k4) {
            const float4 w0 = Ws4[(4 * k4 + 0) * 32 + c4];
            const float4 w1 = Ws4[(4 * k4 + 1) * 32 + c4];
            const float4 w2 = Ws4[(4 * k4 + 2) * 32 + c4];
            const float4 w3 = Ws4[(4 * k4 + 3) * 32 + c4];
            #pragma unroll
            for (int r = 0; r < 4; ++r) {
                const float4 xv = xs4[(rg * 4 + r) * 32 + k4];
                acc[r].x = fmaf(xv.x, w0.x, acc[r].x);
                acc[r].y = fmaf(xv.x, w0.y, acc[r].y);
                acc[r].z = fmaf(xv.x, w0.z, acc[r].z);
                acc[r].w = fmaf(xv.x, w0.w, acc[r].w);
                acc[r].x = fmaf(xv.y, w1.x, acc[r].x);
                acc[r].y = fmaf(xv.y, w1.y, acc[r].y);
                acc[r].z = fmaf(xv.y, w1.z, acc[r].z);
                acc[r].w = fmaf(xv.y, w1.w, acc[r].w);
                acc[r].x = fmaf(xv.z, w2.x, acc[r].x);
                acc[r].y = fmaf(xv.z, w2.y, acc[r].y);
                acc[r].z = fmaf(xv.z, w2.z, acc[r].z);
                acc[r].w = fmaf(xv.z, w2.w, acc[r].w);
                acc[r].x = fmaf(xv.w, w3.x, acc[r].x);
                acc[r].y = fmaf(xv.w, w3.y, acc[r].y);
                acc[r].z = fmaf(xv.w, w3.z, acc[r].z);
                acc[r].w = fmaf(xv.w, w3.w, acc[r].w);
            }
        }

        #pragma unroll
        for (int r = 0; r < 4; ++r) {
            const int row = row_base + rg * 4 + r;
            if (row < N_NODES) {
                const __half2 p0 = __floats2half2_rn(acc[r].x, acc[r].y);
                const __half2 p1 = __floats2half2_rn(acc[r].z, acc[r].w);
                uint2 pk;
                pk.x = *(const unsigned int*)&p0;
                pk.y = *(const unsigned int*)&p1;
                ((uint2*)h)[row * 32 + c4] = pk;

                float ps = acc[r].x * asv.x + acc[r].y * asv.y +
                           acc[r].z * asv.z + acc[r].w * asv.w;
                float pd = acc[r].x * adv.x + acc[r].y * adv.y +
                           acc[r].z * adv.z + acc[r].w * adv.w;
                ps += __shfl_xor(ps, 1, 64); ps += __shfl_xor(ps, 2, 64);
                pd += __shfl_xor(pd, 1, 64); pd += __shfl_xor(pd, 2, 64);
                if ((c4 & 3) == 0) {
                    a_src[row * 8 + head] = ps;
                    a_dst[row * 8 + head] = pd;
                }
            }
        }
        __syncthreads();
    }
}

// ---------------------------------------------------------------------------
// CSR build v4. Bucket = dst>>7.
// cntA: LDS bucket histogram -> gcnt.  scanB: bucket bases -> base, cursor.
// splitA v2: BLOCK-LOCAL RUN ALLOCATION. Each block stages its 8192 edges
//   in LDS grouped by bucket, reserves ONE contiguous global run per
//   (block,bucket) via a single atomicAdd (~77K atomics total), and flushes
//   runs contiguously. Runs are written by a single CU/XCD, so L2 assembles
//   full 64B lines -> write amplification ~1.7x (was ~13x: per-edge atomics
//   scattered each line's 16 entries across all 8 XCDs' L2s).
// phaseB: block per bucket: LDS counting sort -> csr, offs, oend.
// ---------------------------------------------------------------------------
__global__ __launch_bounds__(256)
void cntA_kernel(const int* __restrict__ ei, int* __restrict__ gcnt)
{
    __shared__ int lcnt[NB];
    for (int i = threadIdx.x; i < NB; i += 256) lcnt[i] = 0;
    __syncthreads();
    for (int i = blockIdx.x * 256 + threadIdx.x; i < E_EDGES;
         i += gridDim.x * 256) {
        atomicAdd(&lcnt[ei[E_EDGES + i] >> 7], 1);
    }
    __syncthreads();
    for (int i = threadIdx.x; i < NB; i += 256)
        if (lcnt[i] > 0) atomicAdd(&gcnt[i * PAD], lcnt[i]);
}

__global__ __launch_bounds__(512)
void scanB_kernel(const int* __restrict__ gcnt, int* __restrict__ base,
                  int* __restrict__ cursor)
{
    __shared__ int s[512];
    const int t = threadIdx.x;
    const int v = (t < NB) ? gcnt[t * PAD] : 0;
    s[t] = v;
    __syncthreads();
    #pragma unroll
    for (int d = 1; d < 512; d <<= 1) {
        int x = (t >= d) ? s[t - d] : 0;
        __syncthreads();
        s[t] += x;
        __syncthreads();
    }
    if (t < NB) {
        const int e = s[t] - v;          // exclusive
        base[t] = e;
        cursor[t * PAD] = e;
    }
    if (t == NB - 1) base[NB] = s[t];    // == E_EDGES
}

__global__ __launch_bounds__(256)
void splitA_kernel(const int* __restrict__ ei, int* __restrict__ cursor,
                   unsigned int* __restrict__ bpairs)
{
    __shared__ int scan[512];           // bucket histogram -> inclusive scan
    __shared__ int loff[NB];            // exclusive stage offsets
    __shared__ int lcur[NB];            // stage fill cursors
    __shared__ int gbase[NB];           // reserved global run bases
    __shared__ unsigned int stage[CHUNK];

    const int t = threadIdx.x;
    const int cbase = blockIdx.x * CHUNK;

    for (int i = t; i < 512; i += 256) scan[i] = 0;
    __syncthreads();

    // pass 1: histogram; cache dst in registers (static indexing -> VGPRs)
    int dreg[KPT];
    #pragma unroll
    for (int k = 0; k < KPT; ++k) {
        const int i = cbase + k * 256 + t;
        int d = -1;
        if (i < E_EDGES) {
            d = ei[E_EDGES + i];
            atomicAdd(&scan[d >> 7], 1);
        }
        dreg[k] = d;
    }
    __syncthreads();

    // inclusive scan over 512 slots (256 threads x 2 elements)
    for (int d = 1; d < 512; d <<= 1) {
        const int x0 = (t >= d) ? scan[t - d] : 0;
        const int x1 = scan[t + 256 - d];   // t+256 >= 256 >= d always
        __syncthreads();
        scan[t] += x0;
        scan[t + 256] += x1;
        __syncthreads();
    }

    // reserve one contiguous global run per non-empty bucket
    for (int b = t; b < NB; b += 256) {
        const int inc = scan[b];
        const int exc = b ? scan[b - 1] : 0;
        const int c = inc - exc;
        loff[b] = exc;
        lcur[b] = 0;
        if (c > 0) gbase[b] = atomicAdd(&cursor[b * PAD], c);
    }
    __syncthreads();

    // pass 2: stage grouped by bucket (src re-read; dst from registers)
    #pragma unroll
    for (int k = 0; k < KPT; ++k) {
        const int i = cbase + k * 256 + t;
        if (i < E_EDGES) {
            const int s = ei[i];
            const int d = dreg[k];
            const int b = d >> 7;
            const int l = atomicAdd(&lcur[b], 1);
            stage[loff[b] + l] = ((unsigned)d << 16) | (unsigned)s;
        }
    }
    __syncthreads();

    // flush: contiguous runs to global; bucket found by binary search
    const int total = scan[NB - 1];
    for (int i = t; i < total; i += 256) {
        int lo = 0, hi = NB - 1;
        while (lo < hi) {                 // largest b with loff[b] <= i
            const int mid = (lo + hi + 1) >> 1;
            if (loff[mid] <= i) lo = mid; else hi = mid - 1;
        }
        bpairs[gbase[lo] + (i - loff[lo])] = stage[i];
    }
}

__global__ __launch_bounds__(256)
void phaseB_kernel(const int* __restrict__ base,
                   const unsigned int* __restrict__ bpairs,
                   int* __restrict__ csr, int* __restrict__ offs,
                   int* __restrict__ oend)
{
    const int b  = blockIdx.x;
    const int lo = base[b];
    const int hi = base[b + 1];
    const int node0 = b << 7;
    const int t = threadIdx.x;

    __shared__ int cnt[128], loff[128], cur[128];
    if (t < 128) cnt[t] = 0;
    __syncthreads();

    for (int i = lo + t; i < hi; i += 256) {
        const int ld = (int)(bpairs[i] >> 16) - node0;
        atomicAdd(&cnt[ld], 1);
    }
    __syncthreads();

    if (t < 128) loff[t] = cnt[t];
    __syncthreads();
    #pragma unroll
    for (int d = 1; d < 128; d <<= 1) {
        int x = (t >= d && t < 128) ? loff[t - d] : 0;
        __syncthreads();
        if (t < 128) loff[t] += x;
        __syncthreads();
    }
    if (t < 128) {
        const int e = loff[t] - cnt[t];  // exclusive
        cur[t] = e;
        const int node = node0 + t;
        if (node < N_NODES) {
            offs[node] = lo + e;
            oend[node] = lo + e + cnt[t];
        }
    }
    __syncthreads();

    for (int i = lo + t; i < hi; i += 256) {
        const unsigned p = bpairs[i];
        const int ld = (int)(p >> 16) - node0;
        const int pos = lo + atomicAdd(&cur[ld], 1);
        csr[pos] = (int)(p & 0xFFFFu);
    }
}

// ---------------------------------------------------------------------------
// Kernel 3: fused softmax + aggregation. One wave per destination node.
// fp16 h gather (4B/lane); 8-way edge unroll keeps 8 gathers in flight.
// ---------------------------------------------------------------------------
__global__ __launch_bounds__(256)
void aggregate_kernel(const int* __restrict__ offs, const int* __restrict__ oend,
                      const int* __restrict__ csr_src,
                      const __half* __restrict__ h, const float* __restrict__ a_src,
                      const float* __restrict__ a_dst, const float* __restrict__ bias,
                      float* __restrict__ out)
{
    const int node = blockIdx.x * 4 + (threadIdx.x >> 6);
    if (node >= N_NODES) return;
    const int lane = threadIdx.x & 63;
    const int head = lane >> 3;

    const int start = offs[node];
    const int end   = oend[node];
    const float ad  = a_dst[node * 8 + head];
    const __half2* __restrict__ h2 = (const __half2*)h;

    float accx = 0.f, accy = 0.f, den = 0.f;
    int j = start;
    for (; j + 8 <= end; j += 8) {
        int s[8];
        #pragma unroll
        for (int u = 0; u < 8; ++u) s[u] = csr_src[j + u];
        float lg[8];
        #pragma unroll
        for (int u = 0; u < 8; ++u) lg[u] = a_src[s[u] * 8 + head] + ad;
        __half2 hv[8];
        #pragma unroll
        for (int u = 0; u < 8; ++u) hv[u] = h2[s[u] * 64 + lane];
        #pragma unroll
        for (int u = 0; u < 8; ++u) {
            const float e  = (lg[u] > 0.f) ? lg[u] : lg[u] * NEG_SLOPE;
            const float ex = __expf(e);
            const float2 f = __half22float2(hv[u]);
            accx = fmaf(ex, f.x, accx);
            accy = fmaf(ex, f.y, accy);
            den += ex;
        }
    }
    for (; j < end; ++j) {
        const int src = csr_src[j];
        const float logit = a_src[src * 8 + head] + ad;
        const float e  = (logit > 0.f) ? logit : logit * NEG_SLOPE;
        const float ex = __expf(e);
        const float2 f = __half22float2(h2[src * 64 + lane]);
        accx = fmaf(ex, f.x, accx);
        accy = fmaf(ex, f.y, accy);
        den += ex;
    }
    const float inv = 1.0f / (den + 1e-16f);
    const float2 b = ((const float2*)bias)[lane];
    float2 res;
    res.x = fmaxf(fmaf(accx, inv, b.x), 0.f);
    res.y = fmaxf(fmaf(accy, inv, b.y), 0.f);
    ((float2*)out)[node * 64 + lane] = res;
}

// ---------------------------------------------------------------------------
extern "C" void kernel_launch(void* const* d_in, const int* in_sizes, int n_in,
                              void* d_out, int out_size, void* d_ws, size_t ws_size,
                              hipStream_t stream)
{
    const float* x       = (const float*)d_in[0];
    // d_in[1] = x_0 (unused by reference)
    const float* W       = (const float*)d_in[2];
    const float* att_src = (const float*)d_in[3];
    const float* att_dst = (const float*)d_in[4];
    const float* bias    = (const float*)d_in[5];
    const int*   ei      = (const int*)d_in[6];   // [2][E]: row0=src, row1=dst

    float* out = (float*)d_out;

    // workspace layout (~29.5 MB)
    __half* h     = (__half*)d_ws;                        // 12.8 MB
    float* a_src  = (float*)(h + (size_t)N_NODES * HC);   // 1.6 MB
    float* a_dst  = a_src + (size_t)N_NODES * 8;          // 1.6 MB
    int*   offs   = (int*)(a_dst + (size_t)N_NODES * 8);  // 200 KB
    int*   oend   = offs + N_NODES;                       // 200 KB
    int*   gcnt   = oend + N_NODES;                       // NB*PAD ints
    int*   base   = gcnt + NB * PAD;                      // NB+1 ints
    int*   cursor = base + (NB + 1);                      // NB*PAD ints
    unsigned int* bpairs = (unsigned int*)(cursor + NB * PAD); // 6.4 MB
    int*   csr    = (int*)(bpairs + E_EDGES);             // 6.4 MB

    // 1) projection + attention logits
    hipLaunchKernelGGL(gemm_attn_kernel, dim3(512), dim3(256), 0, stream,
                       x, W, att_src, att_dst, h, a_src, a_dst);

    // 2) CSR build (two-phase bucket sort, block-local run allocation)
    hipMemsetAsync(gcnt, 0, (size_t)NB * PAD * sizeof(int), stream);
    hipLaunchKernelGGL(cntA_kernel, dim3(256), dim3(256), 0, stream, ei, gcnt);
    hipLaunchKernelGGL(scanB_kernel, dim3(1), dim3(512), 0, stream,
                       gcnt, base, cursor);
    hipLaunchKernelGGL(splitA_kernel, dim3((E_EDGES + CHUNK - 1) / CHUNK),
                       dim3(256), 0, stream, ei, cursor, bpairs);
    hipLaunchKernelGGL(phaseB_kernel, dim3(NB), dim3(256), 0, stream,
                       base, bpairs, csr, offs, oend);

    // 3) fused softmax + weighted aggregation (+bias +relu)
    hipLaunchKernelGGL(aggregate_kernel, dim3((N_NODES + 3) / 4), dim3(256), 0,
                       stream, offs, oend, csr, h, a_src, a_dst, bias, out);
}

// Round 18
// 276.662 us; speedup vs baseline: 1.8158x; 1.0043x over previous
//
#include <hip/hip_runtime.h>
#include <hip/hip_fp16.h>
#include <math.h>

#define N_NODES 50000
#define E_EDGES 1600000
#define IN_C 128
#define HC 128          // HEADS*OUT_C
#define NEG_SLOPE 0.2f
#define PAD 16          // one int32 counter per 64B cache line
#define NB 391          // buckets: 128 nodes each, ceil(50000/128)
#define CHUNK 8192      // edges per splitA block
#define KPT 32          // edges per thread (256 threads)

// ---------------------------------------------------------------------------
// Kernel 1: h = x @ W  (50000x128 @ 128x128), fused a_src/a_dst epilogue.
// h stored fp16 (halves aggregate gather traffic; |h|~N(0,1): range safe).
// ---------------------------------------------------------------------------
__global__ __launch_bounds__(256, 2)
void gemm_attn_kernel(const float* __restrict__ x, const float* __restrict__ W,
                      const float* __restrict__ att_src, const float* __restrict__ att_dst,
                      __half* __restrict__ h, float* __restrict__ a_src,
                      float* __restrict__ a_dst)
{
    __shared__ float Ws[128 * 128];   // 64 KB
    __shared__ float xs[32 * 128];    // 16 KB

    const int tid = threadIdx.x;
    const int c4  = tid & 31;
    const int rg  = tid >> 5;

    for (int i = tid; i < 128 * 128 / 4; i += 256)
        ((float4*)Ws)[i] = ((const float4*)W)[i];

    const float4 asv = ((const float4*)att_src)[c4];
    const float4 adv = ((const float4*)att_dst)[c4];
    const int head = c4 >> 2;

    const float4* Ws4 = (const float4*)Ws;
    const float4* xs4 = (const float4*)xs;

    for (int tile = blockIdx.x; tile * 32 < N_NODES; tile += gridDim.x) {
        const int row_base = tile * 32;
        for (int i = tid; i < 32 * 128 / 4; i += 256) {
            const int r  = i >> 5;
            const int gr = row_base + r;
            float4 v = make_float4(0.f, 0.f, 0.f, 0.f);
            if (gr < N_NODES) v = ((const float4*)x)[gr * 32 + (i & 31)];
            ((float4*)xs)[i] = v;
        }
        __syncthreads();

        float4 acc[4];
        #pragma unroll
        for (int r = 0; r < 4; ++r) acc[r] = make_float4(0.f, 0.f, 0.f, 0.f);

        #pragma unroll 4
        for (int k4 = 0; k4 < 32; ++k4) {
            const float4 w0 = Ws4[(4 * k4 + 0) * 32 + c4];
            const float4 w1 = Ws4[(4 * k4 + 1) * 32 + c4];
            const float4 w2 = Ws4[(4 * k4 + 2) * 32 + c4];
            const float4 w3 = Ws4[(4 * k4 + 3) * 32 + c4];
            #pragma unroll
            for (int r = 0; r < 4; ++r) {
                const float4 xv = xs4[(rg * 4 + r) * 32 + k4];
                acc[r].x = fmaf(xv.x, w0.x, acc[r].x);
                acc[r].y = fmaf(xv.x, w0.y, acc[r].y);
                acc[r].z = fmaf(xv.x, w0.z, acc[r].z);
                acc[r].w = fmaf(xv.x, w0.w, acc[r].w);
                acc[r].x = fmaf(xv.y, w1.x, acc[r].x);
                acc[r].y = fmaf(xv.y, w1.y, acc[r].y);
                acc[r].z = fmaf(xv.y, w1.z, acc[r].z);
                acc[r].w = fmaf(xv.y, w1.w, acc[r].w);
                acc[r].x = fmaf(xv.z, w2.x, acc[r].x);
                acc[r].y = fmaf(xv.z, w2.y, acc[r].y);
                acc[r].z = fmaf(xv.z, w2.z, acc[r].z);
                acc[r].w = fmaf(xv.z, w2.w, acc[r].w);
                acc[r].x = fmaf(xv.w, w3.x, acc[r].x);
                acc[r].y = fmaf(xv.w, w3.y, acc[r].y);
                acc[r].z = fmaf(xv.w, w3.z, acc[r].z);
                acc[r].w = fmaf(xv.w, w3.w, acc[r].w);
            }
        }

        #pragma unroll
        for (int r = 0; r < 4; ++r) {
            const int row = row_base + rg * 4 + r;
            if (row < N_NODES) {
                const __half2 p0 = __floats2half2_rn(acc[r].x, acc[r].y);
                const __half2 p1 = __floats2half2_rn(acc[r].z, acc[r].w);
                uint2 pk;
                pk.x = *(const unsigned int*)&p0;
                pk.y = *(const unsigned int*)&p1;
                ((uint2*)h)[row * 32 + c4] = pk;

                float ps = acc[r].x * asv.x + acc[r].y * asv.y +
                           acc[r].z * asv.z + acc[r].w * asv.w;
                float pd = acc[r].x * adv.x + acc[r].y * adv.y +
                           acc[r].z * adv.z + acc[r].w * adv.w;
                ps += __shfl_xor(ps, 1, 64); ps += __shfl_xor(ps, 2, 64);
                pd += __shfl_xor(pd, 1, 64); pd += __shfl_xor(pd, 2, 64);
                if ((c4 & 3) == 0) {
                    a_src[row * 8 + head] = ps;
                    a_dst[row * 8 + head] = pd;
                }
            }
        }
        __syncthreads();
    }
}

// ---------------------------------------------------------------------------
// CSR build v4. Bucket = dst>>7. (unchanged from R10 — verified working)
// ---------------------------------------------------------------------------
__global__ __launch_bounds__(256)
void cntA_kernel(const int* __restrict__ ei, int* __restrict__ gcnt)
{
    __shared__ int lcnt[NB];
    for (int i = threadIdx.x; i < NB; i += 256) lcnt[i] = 0;
    __syncthreads();
    for (int i = blockIdx.x * 256 + threadIdx.x; i < E_EDGES;
         i += gridDim.x * 256) {
        atomicAdd(&lcnt[ei[E_EDGES + i] >> 7], 1);
    }
    __syncthreads();
    for (int i = threadIdx.x; i < NB; i += 256)
        if (lcnt[i] > 0) atomicAdd(&gcnt[i * PAD], lcnt[i]);
}

__global__ __launch_bounds__(512)
void scanB_kernel(const int* __restrict__ gcnt, int* __restrict__ base,
                  int* __restrict__ cursor)
{
    __shared__ int s[512];
    const int t = threadIdx.x;
    const int v = (t < NB) ? gcnt[t * PAD] : 0;
    s[t] = v;
    __syncthreads();
    #pragma unroll
    for (int d = 1; d < 512; d <<= 1) {
        int x = (t >= d) ? s[t - d] : 0;
        __syncthreads();
        s[t] += x;
        __syncthreads();
    }
    if (t < NB) {
        const int e = s[t] - v;          // exclusive
        base[t] = e;
        cursor[t * PAD] = e;
    }
    if (t == NB - 1) base[NB] = s[t];    // == E_EDGES
}

__global__ __launch_bounds__(256)
void splitA_kernel(const int* __restrict__ ei, int* __restrict__ cursor,
                   unsigned int* __restrict__ bpairs)
{
    __shared__ int scan[512];           // bucket histogram -> inclusive scan
    __shared__ int loff[NB];            // exclusive stage offsets
    __shared__ int lcur[NB];            // stage fill cursors
    __shared__ int gbase[NB];           // reserved global run bases
    __shared__ unsigned int stage[CHUNK];

    const int t = threadIdx.x;
    const int cbase = blockIdx.x * CHUNK;

    for (int i = t; i < 512; i += 256) scan[i] = 0;
    __syncthreads();

    // pass 1: histogram; cache dst in registers (static indexing -> VGPRs)
    int dreg[KPT];
    #pragma unroll
    for (int k = 0; k < KPT; ++k) {
        const int i = cbase + k * 256 + t;
        int d = -1;
        if (i < E_EDGES) {
            d = ei[E_EDGES + i];
            atomicAdd(&scan[d >> 7], 1);
        }
        dreg[k] = d;
    }
    __syncthreads();

    // inclusive scan over 512 slots (256 threads x 2 elements)
    for (int d = 1; d < 512; d <<= 1) {
        const int x0 = (t >= d) ? scan[t - d] : 0;
        const int x1 = scan[t + 256 - d];   // t+256 >= 256 >= d always
        __syncthreads();
        scan[t] += x0;
        scan[t + 256] += x1;
        __syncthreads();
    }

    // reserve one contiguous global run per non-empty bucket
    for (int b = t; b < NB; b += 256) {
        const int inc = scan[b];
        const int exc = b ? scan[b - 1] : 0;
        const int c = inc - exc;
        loff[b] = exc;
        lcur[b] = 0;
        if (c > 0) gbase[b] = atomicAdd(&cursor[b * PAD], c);
    }
    __syncthreads();

    // pass 2: stage grouped by bucket (src re-read; dst from registers)
    #pragma unroll
    for (int k = 0; k < KPT; ++k) {
        const int i = cbase + k * 256 + t;
        if (i < E_EDGES) {
            const int s = ei[i];
            const int d = dreg[k];
            const int b = d >> 7;
            const int l = atomicAdd(&lcur[b], 1);
            stage[loff[b] + l] = ((unsigned)d << 16) | (unsigned)s;
        }
    }
    __syncthreads();

    // flush: contiguous runs to global; bucket found by binary search
    const int total = scan[NB - 1];
    for (int i = t; i < total; i += 256) {
        int lo = 0, hi = NB - 1;
        while (lo < hi) {                 // largest b with loff[b] <= i
            const int mid = (lo + hi + 1) >> 1;
            if (loff[mid] <= i) lo = mid; else hi = mid - 1;
        }
        bpairs[gbase[lo] + (i - loff[lo])] = stage[i];
    }
}

__global__ __launch_bounds__(256)
void phaseB_kernel(const int* __restrict__ base,
                   const unsigned int* __restrict__ bpairs,
                   int* __restrict__ csr, int* __restrict__ offs,
                   int* __restrict__ oend)
{
    const int b  = blockIdx.x;
    const int lo = base[b];
    const int hi = base[b + 1];
    const int node0 = b << 7;
    const int t = threadIdx.x;

    __shared__ int cnt[128], loff[128], cur[128];
    if (t < 128) cnt[t] = 0;
    __syncthreads();

    for (int i = lo + t; i < hi; i += 256) {
        const int ld = (int)(bpairs[i] >> 16) - node0;
        atomicAdd(&cnt[ld], 1);
    }
    __syncthreads();

    if (t < 128) loff[t] = cnt[t];
    __syncthreads();
    #pragma unroll
    for (int d = 1; d < 128; d <<= 1) {
        int x = (t >= d && t < 128) ? loff[t - d] : 0;
        __syncthreads();
        if (t < 128) loff[t] += x;
        __syncthreads();
    }
    if (t < 128) {
        const int e = loff[t] - cnt[t];  // exclusive
        cur[t] = e;
        const int node = node0 + t;
        if (node < N_NODES) {
            offs[node] = lo + e;
            oend[node] = lo + e + cnt[t];
        }
    }
    __syncthreads();

    for (int i = lo + t; i < hi; i += 256) {
        const unsigned p = bpairs[i];
        const int ld = (int)(p >> 16) - node0;
        const int pos = lo + atomicAdd(&cur[ld], 1);
        csr[pos] = (int)(p & 0xFFFFu);
    }
}

// ---------------------------------------------------------------------------
// Kernel 3 v3: fused softmax + aggregation, 2 EDGES PER WAVE.
// Wave split into halves (hi = lane>>5); half hi processes edge j+2u+hi.
// Each lane loads 4 channels (uint2 = 4 fp16) at h4[s*32+l5]: 32 lanes x 8B
// = full 256B row per half-wave. Per-edge VALU (addr chains, exp, fma) now
// serves 2 edges per wave-instruction -> halves the VALU-bound cost seen in
// R15 (VALUBusy 73%). Epilogue: shfl_xor(32) cross-half reduce, hi==0 writes.
// ---------------------------------------------------------------------------
__global__ __launch_bounds__(256)
void aggregate_kernel(const int* __restrict__ offs, const int* __restrict__ oend,
                      const int* __restrict__ csr_src,
                      const __half* __restrict__ h, const float* __restrict__ a_src,
                      const float* __restrict__ a_dst, const float* __restrict__ bias,
                      float* __restrict__ out)
{
    const int node = blockIdx.x * 4 + (threadIdx.x >> 6);
    if (node >= N_NODES) return;
    const int lane = threadIdx.x & 63;
    const int hi   = lane >> 5;        // which edge of the pair
    const int l5   = lane & 31;        // quad-channel index: chans 4*l5..+3
    const int head = l5 >> 2;          // 16 chans/head / 4 per lane

    const int start = offs[node];
    const int end   = oend[node];
    const float ad  = a_dst[node * 8 + head];
    const uint2* __restrict__ h4 = (const uint2*)h;   // 4 halves per elem

    float4 acc = make_float4(0.f, 0.f, 0.f, 0.f);
    float den = 0.f;
    int j = start;
    for (; j + 8 <= end; j += 8) {          // 8 edges/iter: 4 per half
        int s[4];
        #pragma unroll
        for (int u = 0; u < 4; ++u) s[u] = csr_src[j + 2 * u + hi];
        float lg[4];
        #pragma unroll
        for (int u = 0; u < 4; ++u) lg[u] = a_src[s[u] * 8 + head] + ad;
        uint2 hv[4];
        #pragma unroll
        for (int u = 0; u < 4; ++u) hv[u] = h4[s[u] * 32 + l5];
        #pragma unroll
        for (int u = 0; u < 4; ++u) {
            const float e  = (lg[u] > 0.f) ? lg[u] : lg[u] * NEG_SLOPE;
            const float ex = __expf(e);
            const float2 f0 = __half22float2(*(const __half2*)&hv[u].x);
            const float2 f1 = __half22float2(*(const __half2*)&hv[u].y);
            acc.x = fmaf(ex, f0.x, acc.x);
            acc.y = fmaf(ex, f0.y, acc.y);
            acc.z = fmaf(ex, f1.x, acc.z);
            acc.w = fmaf(ex, f1.y, acc.w);
            den += ex;
        }
    }
    for (; j < end; j += 2) {               // tail: up to 2 edges/iter
        const int idx   = j + hi;
        const bool valid = idx < end;
        const int src   = csr_src[valid ? idx : j];
        const float logit = a_src[src * 8 + head] + ad;
        const float e  = (logit > 0.f) ? logit : logit * NEG_SLOPE;
        const float ex = valid ? __expf(e) : 0.f;
        const uint2 hv = h4[src * 32 + l5];
        const float2 f0 = __half22float2(*(const __half2*)&hv.x);
        const float2 f1 = __half22float2(*(const __half2*)&hv.y);
        acc.x = fmaf(ex, f0.x, acc.x);
        acc.y = fmaf(ex, f0.y, acc.y);
        acc.z = fmaf(ex, f1.x, acc.z);
        acc.w = fmaf(ex, f1.y, acc.w);
        den += ex;
    }
    // cross-half reduction (edge-parallel partials)
    den   += __shfl_xor(den,   32, 64);
    acc.x += __shfl_xor(acc.x, 32, 64);
    acc.y += __shfl_xor(acc.y, 32, 64);
    acc.z += __shfl_xor(acc.z, 32, 64);
    acc.w += __shfl_xor(acc.w, 32, 64);

    if (hi == 0) {
        const float inv = 1.0f / (den + 1e-16f);
        const float4 b = ((const float4*)bias)[l5];
        float4 r;
        r.x = fmaxf(fmaf(acc.x, inv, b.x), 0.f);
        r.y = fmaxf(fmaf(acc.y, inv, b.y), 0.f);
        r.z = fmaxf(fmaf(acc.z, inv, b.z), 0.f);
        r.w = fmaxf(fmaf(acc.w, inv, b.w), 0.f);
        ((float4*)out)[node * 32 + l5] = r;
    }
}

// ---------------------------------------------------------------------------
extern "C" void kernel_launch(void* const* d_in, const int* in_sizes, int n_in,
                              void* d_out, int out_size, void* d_ws, size_t ws_size,
                              hipStream_t stream)
{
    const float* x       = (const float*)d_in[0];
    // d_in[1] = x_0 (unused by reference)
    const float* W       = (const float*)d_in[2];
    const float* att_src = (const float*)d_in[3];
    const float* att_dst = (const float*)d_in[4];
    const float* bias    = (const float*)d_in[5];
    const int*   ei      = (const int*)d_in[6];   // [2][E]: row0=src, row1=dst

    float* out = (float*)d_out;

    // workspace layout (~29.5 MB)
    __half* h     = (__half*)d_ws;                        // 12.8 MB
    float* a_src  = (float*)(h + (size_t)N_NODES * HC);   // 1.6 MB
    float* a_dst  = a_src + (size_t)N_NODES * 8;          // 1.6 MB
    int*   offs   = (int*)(a_dst + (size_t)N_NODES * 8);  // 200 KB
    int*   oend   = offs + N_NODES;                       // 200 KB
    int*   gcnt   = oend + N_NODES;                       // NB*PAD ints
    int*   base   = gcnt + NB * PAD;                      // NB+1 ints
    int*   cursor = base + (NB + 1);                      // NB*PAD ints
    unsigned int* bpairs = (unsigned int*)(cursor + NB * PAD); // 6.4 MB
    int*   csr    = (int*)(bpairs + E_EDGES);             // 6.4 MB

    // 1) projection + attention logits
    hipLaunchKernelGGL(gemm_attn_kernel, dim3(512), dim3(256), 0, stream,
                       x, W, att_src, att_dst, h, a_src, a_dst);

    // 2) CSR build (two-phase bucket sort, block-local run allocation)
    hipMemsetAsync(gcnt, 0, (size_t)NB * PAD * sizeof(int), stream);
    hipLaunchKernelGGL(cntA_kernel, dim3(256), dim3(256), 0, stream, ei, gcnt);
    hipLaunchKernelGGL(scanB_kernel, dim3(1), dim3(512), 0, stream,
                       gcnt, base, cursor);
    hipLaunchKernelGGL(splitA_kernel, dim3((E_EDGES + CHUNK - 1) / CHUNK),
                       dim3(256), 0, stream, ei, cursor, bpairs);
    hipLaunchKernelGGL(phaseB_kernel, dim3(NB), dim3(256), 0, stream,
                       base, bpairs, csr, offs, oend);

    // 3) fused softmax + weighted aggregation (+bias +relu)
    hipLaunchKernelGGL(aggregate_kernel, dim3((N_NODES + 3) / 4), dim3(256), 0,
                       stream, offs, oend, csr, h, a_src, a_dst, bias, out);
}